// Round 10
// baseline (1743.896 us; speedup 1.0000x reference)
//
#include <hip/hip_runtime.h>
#include <hip/hip_bf16.h>

#define BATCH 8192
#define SDIM  256
#define HID   128
#define LAT   64
#define NCODE 16384

// ws layout (floats): cbT [16][16384] float4 = 1048576 f4 -> 4 MB
//                     cnorm[16384]                        -> 64 KB
//                     ze   [8192*64]                      -> 2 MB
//                     zn   [8192]                         -> 32 KB
#define WS_CBT   0
#define WS_CNORM (16 * 16384 * 4)          // float index
#define WS_ZE    (WS_CNORM + NCODE)
#define WS_ZN    (WS_ZE + BATCH * LAT)

// ---------------- kernel 0: codebook transpose + norms ----------------
// cbT[kk][code] (float4 per entry) so the hot loop's lane-adjacent codes are
// contiguous 16B -> perfectly coalesced 1KB/wave loads. cnorm in the SAME
// sequential fmaf order as r9's in-loop cc (bit-identical scores).
__global__ void kprep_kernel(const float* __restrict__ cb, float* __restrict__ ws) {
  const int c = blockIdx.x * 256 + threadIdx.x;
  const float4* cb4 = reinterpret_cast<const float4*>(cb);
  float4* cbT4 = reinterpret_cast<float4*>(ws + WS_CBT);
  float* cnorm = ws + WS_CNORM;
  float s = 0.f;
#pragma unroll
  for (int q = 0; q < 16; ++q) {
    float4 v = cb4[c * 16 + q];
    s = fmaf(v.x, v.x, s); s = fmaf(v.y, v.y, s);
    s = fmaf(v.z, v.z, s); s = fmaf(v.w, v.w, s);
    cbT4[q * NCODE + c] = v;
  }
  cnorm[c] = s;
}

// ---------------- kernel 1: encoder (r9-proven phases A/B) ----------------
// Writes z_e rows + row norms to ws. Arithmetic identical to the passing r9.
__global__ __launch_bounds__(256, 1) void kenc_kernel(
    const float* __restrict__ x, const float* __restrict__ W1, const float* __restrict__ b1,
    const float* __restrict__ W2, const float* __restrict__ b2, float* __restrict__ ws)
{
  __shared__ float regionA[10624];
  __shared__ float regionB[4224];
  float* xs  = regionA;          // [32][68]
  float* w1t = regionA + 2176;   // [64 k][132 c]
  float* w2  = regionA;          // [128 k][68 c]
  float* hs  = regionB;          // [32][132]
  float* zes = regionB;          // [32][68]

  const int tid  = threadIdx.x;
  const int tx16 = tid & 15, ty16 = tid >> 4;
  const int rowBase = blockIdx.x * 32;

  const float4* x4  = reinterpret_cast<const float4*>(x);
  const float4* W14 = reinterpret_cast<const float4*>(W1);
  const float4* W24 = reinterpret_cast<const float4*>(W2);
  float4* ze4 = reinterpret_cast<float4*>(ws + WS_ZE);
  float* zn = ws + WS_ZN;

  float acc[2][8];
#pragma unroll
  for (int i = 0; i < 2; ++i)
#pragma unroll
    for (int j = 0; j < 8; ++j) acc[i][j] = 0.f;

  for (int kt = 0; kt < 4; ++kt) {
#pragma unroll
    for (int i = 0; i < 2; ++i) {
      int f4i = i * 256 + tid;
      int row = f4i >> 4, k4 = f4i & 15;
      *reinterpret_cast<float4*>(&xs[row * 68 + k4 * 4]) =
          x4[(rowBase + row) * 64 + kt * 16 + k4];
    }
#pragma unroll
    for (int i = 0; i < 8; ++i) {
      int f4i = i * 256 + tid;
      int k = f4i >> 5, c4 = f4i & 31;
      *reinterpret_cast<float4*>(&w1t[k * 132 + c4 * 4]) =
          W14[(kt * 64 + k) * 32 + c4];
    }
    __syncthreads();
#pragma unroll 8
    for (int kk = 0; kk < 64; ++kk) {
      float a0 = xs[(ty16 * 2 + 0) * 68 + kk];
      float a1 = xs[(ty16 * 2 + 1) * 68 + kk];
      float4 bv0 = *reinterpret_cast<const float4*>(&w1t[kk * 132 + tx16 * 8]);
      float4 bv1 = *reinterpret_cast<const float4*>(&w1t[kk * 132 + tx16 * 8 + 4]);
      acc[0][0] = fmaf(a0, bv0.x, acc[0][0]); acc[0][1] = fmaf(a0, bv0.y, acc[0][1]);
      acc[0][2] = fmaf(a0, bv0.z, acc[0][2]); acc[0][3] = fmaf(a0, bv0.w, acc[0][3]);
      acc[0][4] = fmaf(a0, bv1.x, acc[0][4]); acc[0][5] = fmaf(a0, bv1.y, acc[0][5]);
      acc[0][6] = fmaf(a0, bv1.z, acc[0][6]); acc[0][7] = fmaf(a0, bv1.w, acc[0][7]);
      acc[1][0] = fmaf(a1, bv0.x, acc[1][0]); acc[1][1] = fmaf(a1, bv0.y, acc[1][1]);
      acc[1][2] = fmaf(a1, bv0.z, acc[1][2]); acc[1][3] = fmaf(a1, bv0.w, acc[1][3]);
      acc[1][4] = fmaf(a1, bv1.x, acc[1][4]); acc[1][5] = fmaf(a1, bv1.y, acc[1][5]);
      acc[1][6] = fmaf(a1, bv1.z, acc[1][6]); acc[1][7] = fmaf(a1, bv1.w, acc[1][7]);
    }
    __syncthreads();
  }

#pragma unroll
  for (int j = 0; j < 8; ++j) {
    float bb = b1[tx16 * 8 + j];
#pragma unroll
    for (int i = 0; i < 2; ++i)
      hs[(ty16 * 2 + i) * 132 + tx16 * 8 + j] = fmaxf(acc[i][j] + bb, 0.f);
  }
#pragma unroll
  for (int i = 0; i < 8; ++i) {
    int f4i = i * 256 + tid;
    int k = f4i >> 4, c4 = f4i & 15;
    *reinterpret_cast<float4*>(&w2[k * 68 + c4 * 4]) = W24[k * 16 + c4];
  }
  __syncthreads();

  float acc2[2][4];
#pragma unroll
  for (int i = 0; i < 2; ++i)
#pragma unroll
    for (int j = 0; j < 4; ++j) acc2[i][j] = 0.f;
#pragma unroll 8
  for (int kk = 0; kk < 128; ++kk) {
    float a0 = hs[(ty16 * 2 + 0) * 132 + kk];
    float a1 = hs[(ty16 * 2 + 1) * 132 + kk];
    float4 bv = *reinterpret_cast<const float4*>(&w2[kk * 68 + tx16 * 4]);
    acc2[0][0] = fmaf(a0, bv.x, acc2[0][0]); acc2[0][1] = fmaf(a0, bv.y, acc2[0][1]);
    acc2[0][2] = fmaf(a0, bv.z, acc2[0][2]); acc2[0][3] = fmaf(a0, bv.w, acc2[0][3]);
    acc2[1][0] = fmaf(a1, bv.x, acc2[1][0]); acc2[1][1] = fmaf(a1, bv.y, acc2[1][1]);
    acc2[1][2] = fmaf(a1, bv.z, acc2[1][2]); acc2[1][3] = fmaf(a1, bv.w, acc2[1][3]);
  }
  __syncthreads();   // hs/w2 reads done before zes overwrites hs
#pragma unroll
  for (int i = 0; i < 2; ++i) {
    float4 v;
    v.x = acc2[i][0] + b2[tx16 * 4 + 0];
    v.y = acc2[i][1] + b2[tx16 * 4 + 1];
    v.z = acc2[i][2] + b2[tx16 * 4 + 2];
    v.w = acc2[i][3] + b2[tx16 * 4 + 3];
    *reinterpret_cast<float4*>(&zes[(ty16 * 2 + i) * 68 + tx16 * 4]) = v;
    ze4[(rowBase + ty16 * 2 + i) * 16 + tx16] = v;
  }
  __syncthreads();
  if (tid < 32) {   // row norm, same sequential order as r9
    float s = 0.f;
#pragma unroll
    for (int q = 0; q < 16; ++q) {
      float4 v = *reinterpret_cast<const float4*>(&zes[tid * 68 + q * 4]);
      s = fmaf(v.x, v.x, s); s = fmaf(v.y, v.y, s);
      s = fmaf(v.z, v.z, s); s = fmaf(v.w, v.w, s);
    }
    zn[rowBase + tid] = s;
  }
}

// ---------------- kernel 2: distances + argmin + gather + store ----------------
// 256 blocks x 512 threads (8 waves = 2/SIMD). Wave w -> rows 4w..4w+3.
// Codes stream from L2 via coalesced dwordx4 (cbT layout); z-rows broadcast
// from LDS (same-address b128 = conflict-free). NO barriers in the main loop.
__global__ __launch_bounds__(512, 4) void kdist_kernel(
    const float* __restrict__ ws, const float* __restrict__ cb, float* __restrict__ out)
{
  __shared__ float zs[32 * 68];   // 8704 B
  __shared__ float znl[32];

  const int tid = threadIdx.x;
  const int l = tid & 63, w = tid >> 6;     // lane, wave
  const int r0 = w * 4;                     // wave's first local row
  const int rowBase = blockIdx.x * 32;

  const float4* cbT4 = reinterpret_cast<const float4*>(ws + WS_CBT);
  const float* cnorm = ws + WS_CNORM;
  const float4* ze4  = reinterpret_cast<const float4*>(ws + WS_ZE);
  const float* zn    = ws + WS_ZN;
  const float4* cb4  = reinterpret_cast<const float4*>(cb);

  {
    int row = tid >> 4, q = tid & 15;       // 512 threads = 32 rows x 16 f4
    *reinterpret_cast<float4*>(&zs[row * 68 + q * 4]) = ze4[(rowBase + row) * 16 + q];
    if (tid < 32) znl[tid] = zn[rowBase + tid];
  }
  __syncthreads();

  float best[4]; int bidx[4];
#pragma unroll
  for (int i = 0; i < 4; ++i) { best[i] = 3.4e38f; bidx[i] = 0; }

  for (int ct = 0; ct < NCODE / 256; ++ct) {      // 64 code tiles of 256
    const int cbase = ct * 256;
    float cc[4];
#pragma unroll
    for (int j = 0; j < 4; ++j) cc[j] = cnorm[cbase + l + 64 * j];

    float dot[4][4];
#pragma unroll
    for (int i = 0; i < 4; ++i)
#pragma unroll
      for (int j = 0; j < 4; ++j) dot[i][j] = 0.f;

#pragma unroll
    for (int kk = 0; kk < 16; ++kk) {
      const float4* bp = cbT4 + (size_t)kk * NCODE + cbase + l;
      float4 b0 = bp[0], b1 = bp[64], b2 = bp[128], b3 = bp[192];
#pragma unroll
      for (int i = 0; i < 4; ++i) {
        float4 a = *reinterpret_cast<const float4*>(&zs[(r0 + i) * 68 + kk * 4]);
        dot[i][0] = fmaf(a.x, b0.x, dot[i][0]); dot[i][0] = fmaf(a.y, b0.y, dot[i][0]);
        dot[i][0] = fmaf(a.z, b0.z, dot[i][0]); dot[i][0] = fmaf(a.w, b0.w, dot[i][0]);
        dot[i][1] = fmaf(a.x, b1.x, dot[i][1]); dot[i][1] = fmaf(a.y, b1.y, dot[i][1]);
        dot[i][1] = fmaf(a.z, b1.z, dot[i][1]); dot[i][1] = fmaf(a.w, b1.w, dot[i][1]);
        dot[i][2] = fmaf(a.x, b2.x, dot[i][2]); dot[i][2] = fmaf(a.y, b2.y, dot[i][2]);
        dot[i][2] = fmaf(a.z, b2.z, dot[i][2]); dot[i][2] = fmaf(a.w, b2.w, dot[i][2]);
        dot[i][3] = fmaf(a.x, b3.x, dot[i][3]); dot[i][3] = fmaf(a.y, b3.y, dot[i][3]);
        dot[i][3] = fmaf(a.z, b3.z, dot[i][3]); dot[i][3] = fmaf(a.w, b3.w, dot[i][3]);
      }
    }
#pragma unroll
    for (int j = 0; j < 4; ++j) {
      int code = cbase + l + 64 * j;
#pragma unroll
      for (int i = 0; i < 4; ++i) {
        float s = (znl[r0 + i] - 2.f * dot[i][j]) + cc[j];   // np order: (zz-2dot)+cc
        if (s < best[i]) { best[i] = s; bidx[i] = code; }    // strict <: first occurrence
      }
    }
  }

  // full 64-lane butterfly reduce (value, then smaller index on ties)
#pragma unroll
  for (int i = 0; i < 4; ++i) {
    float b_ = best[i]; int x_ = bidx[i];
#pragma unroll
    for (int m = 1; m < 64; m <<= 1) {
      float ob = __shfl_xor(b_, m);
      int   oi = __shfl_xor(x_, m);
      if (ob < b_ || (ob == b_ && oi < x_)) { b_ = ob; x_ = oi; }
    }
    const int bi = x_ & (NCODE - 1);        // defensive clamp
    const int row = rowBase + r0 + i;
    if (l < 16) {                           // 16 lanes x float4 = 64 cols
      float4 c = cb4[bi * 16 + l];
      float4 z = *reinterpret_cast<const float4*>(&zs[(r0 + i) * 68 + l * 4]);
      float4 r;
      r.x = z.x + (c.x - z.x);
      r.y = z.y + (c.y - z.y);
      r.z = z.z + (c.z - z.z);
      r.w = z.w + (c.w - z.w);
      *reinterpret_cast<float4*>(&out[row * 64 + l * 4]) = r;
    }
    if (l == 0) out[BATCH * LAT + row] = (float)bi;
  }
}

extern "C" void kernel_launch(void* const* d_in, const int* in_sizes, int n_in,
                              void* d_out, int out_size, void* d_ws, size_t ws_size,
                              hipStream_t stream)
{
  const float *x = (const float*)d_in[0], *W1 = (const float*)d_in[1],
              *b1 = (const float*)d_in[2], *W2 = (const float*)d_in[3],
              *b2 = (const float*)d_in[4], *cb = (const float*)d_in[5];
  for (int i = 0; i < n_in; ++i) {
    const float* p = (const float*)d_in[i];
    switch (in_sizes[i]) {
      case BATCH * SDIM:  x  = p; break;
      case SDIM * HID:    W1 = p; break;
      case HID:           b1 = p; break;
      case HID * LAT:     W2 = p; break;
      case LAT:           b2 = p; break;
      case NCODE * LAT:   cb = p; break;
      default: break;
    }
  }
  float* ws  = (float*)d_ws;   // ~6.2 MB used
  float* out = (float*)d_out;  // f32: z_q [8192*64] then indices [8192]

  hipLaunchKernelGGL(kprep_kernel, dim3(NCODE / 256), dim3(256), 0, stream, cb, ws);
  hipLaunchKernelGGL(kenc_kernel, dim3(BATCH / 32), dim3(256), 0, stream,
                     x, W1, b1, W2, b2, ws);
  hipLaunchKernelGGL(kdist_kernel, dim3(BATCH / 32), dim3(512), 0, stream,
                     ws, cb, out);
}

// Round 11
// 347.320 us; speedup vs baseline: 5.0210x; 5.0210x over previous
//
#include <hip/hip_runtime.h>
#include <hip/hip_bf16.h>

#define BATCH 8192
#define SDIM  256
#define HID   128
#define LAT   64
#define NCODE 16384
#define NSPLIT 8

// ws layout (floats)
#define WS_CNORM 0
#define WS_ZE    (WS_CNORM + NCODE)            // 8192*64
#define WS_ZN    (WS_ZE + BATCH * LAT)         // 8192
#define WS_PMIN  (WS_ZN + BATCH)               // 8192*8
#define WS_PIDX  (WS_PMIN + BATCH * NSPLIT)    // 8192*8 (as int)

// ---------------- kernel 0: codebook norms (chain == r9's in-loop cc) ----------------
__global__ void kprep_kernel(const float* __restrict__ cb, float* __restrict__ ws) {
  const int c = blockIdx.x * 256 + threadIdx.x;
  const float4* cb4 = reinterpret_cast<const float4*>(cb);
  float s = 0.f;
#pragma unroll
  for (int q = 0; q < 16; ++q) {
    float4 v = cb4[c * 16 + q];
    s = fmaf(v.x, v.x, s); s = fmaf(v.y, v.y, s);
    s = fmaf(v.z, v.z, s); s = fmaf(v.w, v.w, s);
  }
  ws[WS_CNORM + c] = s;
}

// ---------------- kernel 1: encoder (r9-proven) -> ze + zn in ws ----------------
__global__ __launch_bounds__(256, 1) void kenc_kernel(
    const float* __restrict__ x, const float* __restrict__ W1, const float* __restrict__ b1,
    const float* __restrict__ W2, const float* __restrict__ b2, float* __restrict__ ws)
{
  __shared__ __align__(16) float regionA[10624];
  __shared__ __align__(16) float regionB[4224];
  float* xs  = regionA;          // [32][68]
  float* w1t = regionA + 2176;   // [64 k][132 c]
  float* w2  = regionA;          // [128 k][68 c]
  float* hs  = regionB;          // [32][132]
  float* zes = regionB;          // [32][68]

  const int tid  = threadIdx.x;
  const int tx16 = tid & 15, ty16 = tid >> 4;
  const int rowBase = blockIdx.x * 32;

  const float4* x4  = reinterpret_cast<const float4*>(x);
  const float4* W14 = reinterpret_cast<const float4*>(W1);
  const float4* W24 = reinterpret_cast<const float4*>(W2);
  float4* ze4 = reinterpret_cast<float4*>(ws + WS_ZE);
  float* zn = ws + WS_ZN;

  float acc[2][8];
#pragma unroll
  for (int i = 0; i < 2; ++i)
#pragma unroll
    for (int j = 0; j < 8; ++j) acc[i][j] = 0.f;

  for (int kt = 0; kt < 4; ++kt) {
#pragma unroll
    for (int i = 0; i < 2; ++i) {
      int f4i = i * 256 + tid;
      int row = f4i >> 4, k4 = f4i & 15;
      *reinterpret_cast<float4*>(&xs[row * 68 + k4 * 4]) =
          x4[(rowBase + row) * 64 + kt * 16 + k4];
    }
#pragma unroll
    for (int i = 0; i < 8; ++i) {
      int f4i = i * 256 + tid;
      int k = f4i >> 5, c4 = f4i & 31;
      *reinterpret_cast<float4*>(&w1t[k * 132 + c4 * 4]) =
          W14[(kt * 64 + k) * 32 + c4];
    }
    __syncthreads();
#pragma unroll 8
    for (int kk = 0; kk < 64; ++kk) {
      float a0 = xs[(ty16 * 2 + 0) * 68 + kk];
      float a1 = xs[(ty16 * 2 + 1) * 68 + kk];
      float4 bv0 = *reinterpret_cast<const float4*>(&w1t[kk * 132 + tx16 * 8]);
      float4 bv1 = *reinterpret_cast<const float4*>(&w1t[kk * 132 + tx16 * 8 + 4]);
      acc[0][0] = fmaf(a0, bv0.x, acc[0][0]); acc[0][1] = fmaf(a0, bv0.y, acc[0][1]);
      acc[0][2] = fmaf(a0, bv0.z, acc[0][2]); acc[0][3] = fmaf(a0, bv0.w, acc[0][3]);
      acc[0][4] = fmaf(a0, bv1.x, acc[0][4]); acc[0][5] = fmaf(a0, bv1.y, acc[0][5]);
      acc[0][6] = fmaf(a0, bv1.z, acc[0][6]); acc[0][7] = fmaf(a0, bv1.w, acc[0][7]);
      acc[1][0] = fmaf(a1, bv0.x, acc[1][0]); acc[1][1] = fmaf(a1, bv0.y, acc[1][1]);
      acc[1][2] = fmaf(a1, bv0.z, acc[1][2]); acc[1][3] = fmaf(a1, bv0.w, acc[1][3]);
      acc[1][4] = fmaf(a1, bv1.x, acc[1][4]); acc[1][5] = fmaf(a1, bv1.y, acc[1][5]);
      acc[1][6] = fmaf(a1, bv1.z, acc[1][6]); acc[1][7] = fmaf(a1, bv1.w, acc[1][7]);
    }
    __syncthreads();
  }

#pragma unroll
  for (int j = 0; j < 8; ++j) {
    float bb = b1[tx16 * 8 + j];
#pragma unroll
    for (int i = 0; i < 2; ++i)
      hs[(ty16 * 2 + i) * 132 + tx16 * 8 + j] = fmaxf(acc[i][j] + bb, 0.f);
  }
#pragma unroll
  for (int i = 0; i < 8; ++i) {
    int f4i = i * 256 + tid;
    int k = f4i >> 4, c4 = f4i & 15;
    *reinterpret_cast<float4*>(&w2[k * 68 + c4 * 4]) = W24[k * 16 + c4];
  }
  __syncthreads();

  float acc2[2][4];
#pragma unroll
  for (int i = 0; i < 2; ++i)
#pragma unroll
    for (int j = 0; j < 4; ++j) acc2[i][j] = 0.f;
#pragma unroll 8
  for (int kk = 0; kk < 128; ++kk) {
    float a0 = hs[(ty16 * 2 + 0) * 132 + kk];
    float a1 = hs[(ty16 * 2 + 1) * 132 + kk];
    float4 bv = *reinterpret_cast<const float4*>(&w2[kk * 68 + tx16 * 4]);
    acc2[0][0] = fmaf(a0, bv.x, acc2[0][0]); acc2[0][1] = fmaf(a0, bv.y, acc2[0][1]);
    acc2[0][2] = fmaf(a0, bv.z, acc2[0][2]); acc2[0][3] = fmaf(a0, bv.w, acc2[0][3]);
    acc2[1][0] = fmaf(a1, bv.x, acc2[1][0]); acc2[1][1] = fmaf(a1, bv.y, acc2[1][1]);
    acc2[1][2] = fmaf(a1, bv.z, acc2[1][2]); acc2[1][3] = fmaf(a1, bv.w, acc2[1][3]);
  }
  __syncthreads();
#pragma unroll
  for (int i = 0; i < 2; ++i) {
    float4 v;
    v.x = acc2[i][0] + b2[tx16 * 4 + 0];
    v.y = acc2[i][1] + b2[tx16 * 4 + 1];
    v.z = acc2[i][2] + b2[tx16 * 4 + 2];
    v.w = acc2[i][3] + b2[tx16 * 4 + 3];
    *reinterpret_cast<float4*>(&zes[(ty16 * 2 + i) * 68 + tx16 * 4]) = v;
    ze4[(rowBase + ty16 * 2 + i) * 16 + tx16] = v;
  }
  __syncthreads();
  if (tid < 32) {   // row norm, same sequential chain as r9
    float s = 0.f;
#pragma unroll
    for (int q = 0; q < 16; ++q) {
      float4 v = *reinterpret_cast<const float4*>(&zes[tid * 68 + q * 4]);
      s = fmaf(v.x, v.x, s); s = fmaf(v.y, v.y, s);
      s = fmaf(v.z, v.z, s); s = fmaf(v.w, v.w, s);
    }
    zn[rowBase + tid] = s;
  }
}

// ---------------- kernel 2: GEMM-tiled distances + partial argmin ----------------
// 512 blocks (64 row-blocks x 8 splits; split = bid&7 pins split per XCD L2).
// Block: 128 rows x 2048 codes, K=64. Thread tile 8x8 -> VALU-bound (512 cy
// FMA vs 192 cy LDS per f4-step). 2 blocks/CU (70KB LDS, VGPR<=256 via lb(256,2)).
__global__ __launch_bounds__(256, 2) void kdist_kernel(
    const float* __restrict__ ws_ro, const float* __restrict__ cb,
    float* __restrict__ pmin, int* __restrict__ pidx)
{
  __shared__ __align__(16) float zs[128 * 68];   // 34816 B
  __shared__ __align__(16) float cs[128 * 68];   // 34816 B
  __shared__ float cns[128];
  __shared__ float znl[128];

  const int tid = threadIdx.x;
  const int tx = tid & 15, ty = tid >> 4;
  const int split = blockIdx.x & (NSPLIT - 1);
  const int rb = blockIdx.x >> 3;
  const int rowBase = rb * 128;
  const int cbase0 = split * (NCODE / NSPLIT);

  const float4* ze4  = reinterpret_cast<const float4*>(ws_ro + WS_ZE);
  const float*  zn   = ws_ro + WS_ZN;
  const float*  cnorm = ws_ro + WS_CNORM;
  const float4* cb4  = reinterpret_cast<const float4*>(cb);

  // stage z tile [128][68]
#pragma unroll
  for (int i = 0; i < 8; ++i) {
    int f4i = i * 256 + tid;
    int row = f4i >> 4, q = f4i & 15;
    *reinterpret_cast<float4*>(&zs[row * 68 + q * 4]) = ze4[(rowBase + row) * 16 + q];
  }
  if (tid < 128) znl[tid] = zn[rowBase + tid];

  float best[8]; int bidx[8];
#pragma unroll
  for (int i = 0; i < 8; ++i) { best[i] = 3.4e38f; bidx[i] = 0; }

  for (int t = 0; t < (NCODE / NSPLIT) / 128; ++t) {   // 16 code tiles of 128
    const int c0 = cbase0 + t * 128;
    __syncthreads();   // prev tile's cs readers done; covers zs/znl staging at t=0
#pragma unroll
    for (int i = 0; i < 8; ++i) {
      int f4i = i * 256 + tid;
      int code = f4i >> 4, q = f4i & 15;
      *reinterpret_cast<float4*>(&cs[code * 68 + q * 4]) = cb4[(c0 + code) * 16 + q];
    }
    if (tid < 128) cns[tid] = cnorm[c0 + tid];
    __syncthreads();

    float dot[8][8];
#pragma unroll
    for (int i = 0; i < 8; ++i)
#pragma unroll
      for (int j = 0; j < 8; ++j) dot[i][j] = 0.f;

#pragma unroll 4
    for (int kk = 0; kk < 16; ++kk) {
      float4 a[8];
#pragma unroll
      for (int i = 0; i < 8; ++i)            // 4 addrs/wave -> broadcast, conflict-free
        a[i] = *reinterpret_cast<const float4*>(&zs[(ty * 8 + i) * 68 + kk * 4]);
#pragma unroll
      for (int j = 0; j < 8; ++j) {
        // code = tx + 16j: stride-68 rows -> 4*tx mod 32 banks -> 2-way (free)
        float4 b = *reinterpret_cast<const float4*>(&cs[(tx + 16 * j) * 68 + kk * 4]);
#pragma unroll
        for (int i = 0; i < 8; ++i) {
          dot[i][j] = fmaf(a[i].x, b.x, dot[i][j]);
          dot[i][j] = fmaf(a[i].y, b.y, dot[i][j]);
          dot[i][j] = fmaf(a[i].z, b.z, dot[i][j]);
          dot[i][j] = fmaf(a[i].w, b.w, dot[i][j]);
        }
      }
    }
#pragma unroll
    for (int j = 0; j < 8; ++j) {
      float cc = cns[tx + 16 * j];
      int code = c0 + tx + 16 * j;
#pragma unroll
      for (int i = 0; i < 8; ++i) {
        float s = (znl[ty * 8 + i] - 2.f * dot[i][j]) + cc;   // np order
        if (s < best[i]) { best[i] = s; bidx[i] = code; }     // strict <
      }
    }
  }

  // reduce across the 16 tx lanes of each row group
#pragma unroll
  for (int i = 0; i < 8; ++i) {
    float b_ = best[i]; int x_ = bidx[i];
#pragma unroll
    for (int m = 1; m < 16; m <<= 1) {
      float ob = __shfl_xor(b_, m);
      int   oi = __shfl_xor(x_, m);
      if (ob < b_ || (ob == b_ && oi < x_)) { b_ = ob; x_ = oi; }
    }
    if (tx == 0) {
      int row = rowBase + ty * 8 + i;
      pmin[row * NSPLIT + split] = b_;
      pidx[row * NSPLIT + split] = x_;
    }
  }
}

// ---------------- kernel 3: final argmin across splits + gather + store ----------------
__global__ void kfinal_kernel(const float* __restrict__ ws_ro, const int* __restrict__ pidx,
                              const float* __restrict__ cb, float* __restrict__ out)
{
  const int row = blockIdx.x * 256 + threadIdx.x;
  const float* pmin = ws_ro + WS_PMIN;
  float bb = pmin[row * NSPLIT];
  int   bi = pidx[row * NSPLIT];
#pragma unroll
  for (int s = 1; s < NSPLIT; ++s) {
    float v = pmin[row * NSPLIT + s];
    int  id = pidx[row * NSPLIT + s];
    if (v < bb || (v == bb && id < bi)) { bb = v; bi = id; }
  }
  bi &= (NCODE - 1);

  const float4* cb4 = reinterpret_cast<const float4*>(cb);
  const float4* ze4 = reinterpret_cast<const float4*>(ws_ro + WS_ZE);
#pragma unroll
  for (int q = 0; q < 16; ++q) {
    float4 c = cb4[bi * 16 + q];
    float4 z = ze4[row * 16 + q];
    float4 r;
    r.x = z.x + (c.x - z.x);
    r.y = z.y + (c.y - z.y);
    r.z = z.z + (c.z - z.z);
    r.w = z.w + (c.w - z.w);
    *reinterpret_cast<float4*>(&out[row * 64 + q * 4]) = r;
  }
  out[BATCH * LAT + row] = (float)bi;
}

extern "C" void kernel_launch(void* const* d_in, const int* in_sizes, int n_in,
                              void* d_out, int out_size, void* d_ws, size_t ws_size,
                              hipStream_t stream)
{
  const float *x = (const float*)d_in[0], *W1 = (const float*)d_in[1],
              *b1 = (const float*)d_in[2], *W2 = (const float*)d_in[3],
              *b2 = (const float*)d_in[4], *cb = (const float*)d_in[5];
  for (int i = 0; i < n_in; ++i) {
    const float* p = (const float*)d_in[i];
    switch (in_sizes[i]) {
      case BATCH * SDIM:  x  = p; break;
      case SDIM * HID:    W1 = p; break;
      case HID:           b1 = p; break;
      case HID * LAT:     W2 = p; break;
      case LAT:           b2 = p; break;
      case NCODE * LAT:   cb = p; break;
      default: break;
    }
  }
  float* ws  = (float*)d_ws;   // ~2.7 MB used
  float* out = (float*)d_out;  // f32: z_q [8192*64] then indices [8192]
  float* pmin = ws + WS_PMIN;
  int*   pidx = (int*)(ws + WS_PIDX);

  hipLaunchKernelGGL(kprep_kernel, dim3(NCODE / 256), dim3(256), 0, stream, cb, ws);
  hipLaunchKernelGGL(kenc_kernel, dim3(BATCH / 32), dim3(256), 0, stream,
                     x, W1, b1, W2, b2, ws);
  hipLaunchKernelGGL(kdist_kernel, dim3((BATCH / 128) * NSPLIT), dim3(256), 0, stream,
                     ws, cb, pmin, pidx);
  hipLaunchKernelGGL(kfinal_kernel, dim3(BATCH / 256), dim3(256), 0, stream,
                     ws, pidx, cb, out);
}

// Round 12
// 229.590 us; speedup vs baseline: 7.5957x; 1.5128x over previous
//
#include <hip/hip_runtime.h>
#include <hip/hip_bf16.h>

#define BATCH 8192
#define SDIM  256
#define HID   128
#define LAT   64
#define NCODE 16384
#define NSPLIT 8

typedef __attribute__((ext_vector_type(8)))  short bf16x8;
typedef __attribute__((ext_vector_type(16))) float f32x16;

// ws layout (float indices). ~9.6 MB total.
#define WS_CNORM 0
#define WS_ZE    (WS_CNORM + NCODE)
#define WS_ZN    (WS_ZE + BATCH * LAT)
#define WS_PIDX  (WS_ZN + BATCH)                    // [BATCH][NSPLIT][2] int
#define WS_CBH   (WS_PIDX + BATCH * NSPLIT * 2)     // bf16 [NCODE][64] (permuted frag order)
#define WS_CBL   (WS_CBH + NCODE * LAT / 2)
#define WS_ZEH   (WS_CBL + NCODE * LAT / 2)         // bf16 [BATCH][64] (permuted)
#define WS_ZEL   (WS_ZEH + BATCH * LAT / 2)

__device__ __forceinline__ unsigned short f2bfu(float f) {
  __hip_bfloat16 h = __float2bfloat16(f);
  return __builtin_bit_cast(unsigned short, h);
}
__device__ __forceinline__ float bfu2f(unsigned short u) {
  __hip_bfloat16 h = __builtin_bit_cast(__hip_bfloat16, u);
  return __bfloat162float(h);
}

// ---------------- kernel 0: cnorm (r11 chain) + permuted bf16 hi/lo codebook ----------------
// Fragment permutation per 64-k row: frag(m,h) occupies elems [m*16+h*8, +8) holding
// logical k: {16m+4h+0..3, 16m+8+4h+0..3}  (gfx950 K-doubled MFMA = two stacked K=8 blocks).
// Writer mapping: float4 q=4m+w -> ushort4 at m*16 + ((w&1)*8 + (w&2)*2).
__global__ void kprep_kernel(const float* __restrict__ cb, float* __restrict__ ws) {
  const int c = blockIdx.x * 256 + threadIdx.x;
  const float4* cb4 = reinterpret_cast<const float4*>(cb);
  unsigned short* cbh = reinterpret_cast<unsigned short*>(ws + WS_CBH);
  unsigned short* cbl = reinterpret_cast<unsigned short*>(ws + WS_CBL);
  float4 v[16];
  float s = 0.f;
#pragma unroll
  for (int q = 0; q < 16; ++q) {
    v[q] = cb4[c * 16 + q];
    s = fmaf(v[q].x, v[q].x, s); s = fmaf(v[q].y, v[q].y, s);
    s = fmaf(v[q].z, v[q].z, s); s = fmaf(v[q].w, v[q].w, s);
  }
  ws[WS_CNORM + c] = s;
#pragma unroll
  for (int m = 0; m < 4; ++m) {
#pragma unroll
    for (int w = 0; w < 4; ++w) {
      float4 f = v[4 * m + w];
      const int posoff = ((w & 1) * 8) + ((w & 2) * 2);
      ushort4 hh, ll;
      hh.x = f2bfu(f.x); ll.x = f2bfu(f.x - bfu2f(hh.x));
      hh.y = f2bfu(f.y); ll.y = f2bfu(f.y - bfu2f(hh.y));
      hh.z = f2bfu(f.z); ll.z = f2bfu(f.z - bfu2f(hh.z));
      hh.w = f2bfu(f.w); ll.w = f2bfu(f.w - bfu2f(hh.w));
      *reinterpret_cast<ushort4*>(&cbh[c * 64 + m * 16 + posoff]) = hh;
      *reinterpret_cast<ushort4*>(&cbl[c * 64 + m * 16 + posoff]) = ll;
    }
  }
}

// ---------------- kernel 1: encoder (r11-proven) -> ze, zn, permuted zeh/zel ----------------
__global__ __launch_bounds__(256, 1) void kenc_kernel(
    const float* __restrict__ x, const float* __restrict__ W1, const float* __restrict__ b1,
    const float* __restrict__ W2, const float* __restrict__ b2, float* __restrict__ ws)
{
  __shared__ __align__(16) float regionA[10624];
  __shared__ __align__(16) float regionB[4224];
  float* xs  = regionA;          // [32][68]
  float* w1t = regionA + 2176;   // [64 k][132 c]
  float* w2  = regionA;          // [128 k][68 c]
  float* hs  = regionB;          // [32][132]
  float* zes = regionB;          // [32][68]

  const int tid  = threadIdx.x;
  const int tx16 = tid & 15, ty16 = tid >> 4;
  const int rowBase = blockIdx.x * 32;

  const float4* x4  = reinterpret_cast<const float4*>(x);
  const float4* W14 = reinterpret_cast<const float4*>(W1);
  const float4* W24 = reinterpret_cast<const float4*>(W2);
  float4* ze4 = reinterpret_cast<float4*>(ws + WS_ZE);
  float* zn = ws + WS_ZN;
  unsigned short* zehp = reinterpret_cast<unsigned short*>(ws + WS_ZEH);
  unsigned short* zelp = reinterpret_cast<unsigned short*>(ws + WS_ZEL);

  float acc[2][8];
#pragma unroll
  for (int i = 0; i < 2; ++i)
#pragma unroll
    for (int j = 0; j < 8; ++j) acc[i][j] = 0.f;

  for (int kt = 0; kt < 4; ++kt) {
#pragma unroll
    for (int i = 0; i < 2; ++i) {
      int f4i = i * 256 + tid;
      int row = f4i >> 4, k4 = f4i & 15;
      *reinterpret_cast<float4*>(&xs[row * 68 + k4 * 4]) =
          x4[(rowBase + row) * 64 + kt * 16 + k4];
    }
#pragma unroll
    for (int i = 0; i < 8; ++i) {
      int f4i = i * 256 + tid;
      int k = f4i >> 5, c4 = f4i & 31;
      *reinterpret_cast<float4*>(&w1t[k * 132 + c4 * 4]) =
          W14[(kt * 64 + k) * 32 + c4];
    }
    __syncthreads();
#pragma unroll 8
    for (int kk = 0; kk < 64; ++kk) {
      float a0 = xs[(ty16 * 2 + 0) * 68 + kk];
      float a1 = xs[(ty16 * 2 + 1) * 68 + kk];
      float4 bv0 = *reinterpret_cast<const float4*>(&w1t[kk * 132 + tx16 * 8]);
      float4 bv1 = *reinterpret_cast<const float4*>(&w1t[kk * 132 + tx16 * 8 + 4]);
      acc[0][0] = fmaf(a0, bv0.x, acc[0][0]); acc[0][1] = fmaf(a0, bv0.y, acc[0][1]);
      acc[0][2] = fmaf(a0, bv0.z, acc[0][2]); acc[0][3] = fmaf(a0, bv0.w, acc[0][3]);
      acc[0][4] = fmaf(a0, bv1.x, acc[0][4]); acc[0][5] = fmaf(a0, bv1.y, acc[0][5]);
      acc[0][6] = fmaf(a0, bv1.z, acc[0][6]); acc[0][7] = fmaf(a0, bv1.w, acc[0][7]);
      acc[1][0] = fmaf(a1, bv0.x, acc[1][0]); acc[1][1] = fmaf(a1, bv0.y, acc[1][1]);
      acc[1][2] = fmaf(a1, bv0.z, acc[1][2]); acc[1][3] = fmaf(a1, bv0.w, acc[1][3]);
      acc[1][4] = fmaf(a1, bv1.x, acc[1][4]); acc[1][5] = fmaf(a1, bv1.y, acc[1][5]);
      acc[1][6] = fmaf(a1, bv1.z, acc[1][6]); acc[1][7] = fmaf(a1, bv1.w, acc[1][7]);
    }
    __syncthreads();
  }

#pragma unroll
  for (int j = 0; j < 8; ++j) {
    float bb = b1[tx16 * 8 + j];
#pragma unroll
    for (int i = 0; i < 2; ++i)
      hs[(ty16 * 2 + i) * 132 + tx16 * 8 + j] = fmaxf(acc[i][j] + bb, 0.f);
  }
#pragma unroll
  for (int i = 0; i < 8; ++i) {
    int f4i = i * 256 + tid;
    int k = f4i >> 4, c4 = f4i & 15;
    *reinterpret_cast<float4*>(&w2[k * 68 + c4 * 4]) = W24[k * 16 + c4];
  }
  __syncthreads();

  float acc2[2][4];
#pragma unroll
  for (int i = 0; i < 2; ++i)
#pragma unroll
    for (int j = 0; j < 4; ++j) acc2[i][j] = 0.f;
#pragma unroll 8
  for (int kk = 0; kk < 128; ++kk) {
    float a0 = hs[(ty16 * 2 + 0) * 132 + kk];
    float a1 = hs[(ty16 * 2 + 1) * 132 + kk];
    float4 bv = *reinterpret_cast<const float4*>(&w2[kk * 68 + tx16 * 4]);
    acc2[0][0] = fmaf(a0, bv.x, acc2[0][0]); acc2[0][1] = fmaf(a0, bv.y, acc2[0][1]);
    acc2[0][2] = fmaf(a0, bv.z, acc2[0][2]); acc2[0][3] = fmaf(a0, bv.w, acc2[0][3]);
    acc2[1][0] = fmaf(a1, bv.x, acc2[1][0]); acc2[1][1] = fmaf(a1, bv.y, acc2[1][1]);
    acc2[1][2] = fmaf(a1, bv.z, acc2[1][2]); acc2[1][3] = fmaf(a1, bv.w, acc2[1][3]);
  }
  __syncthreads();
#pragma unroll
  for (int i = 0; i < 2; ++i) {
    float4 v;
    v.x = acc2[i][0] + b2[tx16 * 4 + 0];
    v.y = acc2[i][1] + b2[tx16 * 4 + 1];
    v.z = acc2[i][2] + b2[tx16 * 4 + 2];
    v.w = acc2[i][3] + b2[tx16 * 4 + 3];
    *reinterpret_cast<float4*>(&zes[(ty16 * 2 + i) * 68 + tx16 * 4]) = v;
    const int rowg = rowBase + ty16 * 2 + i;
    ze4[rowg * 16 + tx16] = v;
    // permuted bf16 hi/lo (q=tx16: off = (q>>2)*16 + (q&1)*8 + (q&2)*2)
    ushort4 hh, ll;
    hh.x = f2bfu(v.x); ll.x = f2bfu(v.x - bfu2f(hh.x));
    hh.y = f2bfu(v.y); ll.y = f2bfu(v.y - bfu2f(hh.y));
    hh.z = f2bfu(v.z); ll.z = f2bfu(v.z - bfu2f(hh.z));
    hh.w = f2bfu(v.w); ll.w = f2bfu(v.w - bfu2f(hh.w));
    const int off = ((tx16 >> 2) * 16) + ((tx16 & 1) * 8) + ((tx16 & 2) * 2);
    *reinterpret_cast<ushort4*>(&zehp[rowg * 64 + off]) = hh;
    *reinterpret_cast<ushort4*>(&zelp[rowg * 64 + off]) = ll;
  }
  __syncthreads();
  if (tid < 32) {   // row norm, same sequential chain as r11
    float s = 0.f;
#pragma unroll
    for (int q = 0; q < 16; ++q) {
      float4 v = *reinterpret_cast<const float4*>(&zes[tid * 68 + q * 4]);
      s = fmaf(v.x, v.x, s); s = fmaf(v.y, v.y, s);
      s = fmaf(v.z, v.z, s); s = fmaf(v.w, v.w, s);
    }
    zn[rowBase + tid] = s;
  }
}

// ---------------- kernel 2: MFMA distances -> top-2 nominees per (row, split) ----------------
// 512 blocks (64 row-blocks x 8 splits), 256 thr = 4 independent waves (NO LDS, NO barriers).
// Wave: 32 rows x 2048 codes in 64 tiles of 32. 4-term bf16 hi/lo split, 16 MFMA/tile.
#define LOADB(SET, T) do {                                                        \
    const int code_ = cbase + (T) * 32 + lr;                                      \
    Bh##SET[0] = *reinterpret_cast<const bf16x8*>(&cbh[code_ * 64 +  0 + half * 8]); \
    Bh##SET[1] = *reinterpret_cast<const bf16x8*>(&cbh[code_ * 64 + 16 + half * 8]); \
    Bh##SET[2] = *reinterpret_cast<const bf16x8*>(&cbh[code_ * 64 + 32 + half * 8]); \
    Bh##SET[3] = *reinterpret_cast<const bf16x8*>(&cbh[code_ * 64 + 48 + half * 8]); \
    Bl##SET[0] = *reinterpret_cast<const bf16x8*>(&cbl[code_ * 64 +  0 + half * 8]); \
    Bl##SET[1] = *reinterpret_cast<const bf16x8*>(&cbl[code_ * 64 + 16 + half * 8]); \
    Bl##SET[2] = *reinterpret_cast<const bf16x8*>(&cbl[code_ * 64 + 32 + half * 8]); \
    Bl##SET[3] = *reinterpret_cast<const bf16x8*>(&cbl[code_ * 64 + 48 + half * 8]); \
    cc##SET = cnorm[code_];                                                       \
  } while (0)

#define MFMAEPI(SET, T) do {                                                      \
    const int codeb_ = cbase + (T) * 32 + lr;                                     \
    f32x16 a0_, a1_;                                                              \
    _Pragma("unroll")                                                             \
    for (int r_ = 0; r_ < 16; ++r_) { a0_[r_] = 0.f; a1_[r_] = 0.f; }             \
    a0_ = __builtin_amdgcn_mfma_f32_32x32x16_bf16(Ah[0], Bh##SET[0], a0_, 0, 0, 0); \
    a1_ = __builtin_amdgcn_mfma_f32_32x32x16_bf16(Ah[0], Bl##SET[0], a1_, 0, 0, 0); \
    a0_ = __builtin_amdgcn_mfma_f32_32x32x16_bf16(Ah[1], Bh##SET[1], a0_, 0, 0, 0); \
    a1_ = __builtin_amdgcn_mfma_f32_32x32x16_bf16(Ah[1], Bl##SET[1], a1_, 0, 0, 0); \
    a0_ = __builtin_amdgcn_mfma_f32_32x32x16_bf16(Ah[2], Bh##SET[2], a0_, 0, 0, 0); \
    a1_ = __builtin_amdgcn_mfma_f32_32x32x16_bf16(Ah[2], Bl##SET[2], a1_, 0, 0, 0); \
    a0_ = __builtin_amdgcn_mfma_f32_32x32x16_bf16(Ah[3], Bh##SET[3], a0_, 0, 0, 0); \
    a1_ = __builtin_amdgcn_mfma_f32_32x32x16_bf16(Ah[3], Bl##SET[3], a1_, 0, 0, 0); \
    a0_ = __builtin_amdgcn_mfma_f32_32x32x16_bf16(Al[0], Bh##SET[0], a0_, 0, 0, 0); \
    a1_ = __builtin_amdgcn_mfma_f32_32x32x16_bf16(Al[0], Bl##SET[0], a1_, 0, 0, 0); \
    a0_ = __builtin_amdgcn_mfma_f32_32x32x16_bf16(Al[1], Bh##SET[1], a0_, 0, 0, 0); \
    a1_ = __builtin_amdgcn_mfma_f32_32x32x16_bf16(Al[1], Bl##SET[1], a1_, 0, 0, 0); \
    a0_ = __builtin_amdgcn_mfma_f32_32x32x16_bf16(Al[2], Bh##SET[2], a0_, 0, 0, 0); \
    a1_ = __builtin_amdgcn_mfma_f32_32x32x16_bf16(Al[2], Bl##SET[2], a1_, 0, 0, 0); \
    a0_ = __builtin_amdgcn_mfma_f32_32x32x16_bf16(Al[3], Bh##SET[3], a0_, 0, 0, 0); \
    a1_ = __builtin_amdgcn_mfma_f32_32x32x16_bf16(Al[3], Bl##SET[3], a1_, 0, 0, 0); \
    _Pragma("unroll")                                                             \
    for (int r_ = 0; r_ < 16; ++r_) {                                             \
      float d_ = a0_[r_] + a1_[r_];                                               \
      float s_ = fmaf(-2.f, d_, cc##SET);                                         \
      bool lt1 = s_ < best[r_];                                                   \
      bool lt2 = s_ < bst2[r_];                                                   \
      bst2[r_]  = lt1 ? best[r_] : (lt2 ? s_ : bst2[r_]);                         \
      bidx2[r_] = lt1 ? bidx[r_] : (lt2 ? codeb_ : bidx2[r_]);                    \
      best[r_]  = lt1 ? s_ : best[r_];                                            \
      bidx[r_]  = lt1 ? codeb_ : bidx[r_];                                        \
    }                                                                             \
  } while (0)

__global__ __launch_bounds__(256) void kdist_kernel(float* __restrict__ ws)
{
  const int tid = threadIdx.x;
  const int wv = tid >> 6, l = tid & 63;
  const int half = l >> 5, lr = l & 31;
  const int split = blockIdx.x & (NSPLIT - 1);
  const int rb = blockIdx.x >> 3;
  const int rowBase = rb * 128 + wv * 32;

  const unsigned short* zeh = reinterpret_cast<const unsigned short*>(ws + WS_ZEH);
  const unsigned short* zel = reinterpret_cast<const unsigned short*>(ws + WS_ZEL);
  const unsigned short* cbh = reinterpret_cast<const unsigned short*>(ws + WS_CBH);
  const unsigned short* cbl = reinterpret_cast<const unsigned short*>(ws + WS_CBL);
  const float* cnorm = ws + WS_CNORM;
  int* pidx = reinterpret_cast<int*>(ws + WS_PIDX);

  const int row = rowBase + lr;
  bf16x8 Ah[4], Al[4];
#pragma unroll
  for (int m = 0; m < 4; ++m) {
    Ah[m] = *reinterpret_cast<const bf16x8*>(&zeh[row * 64 + m * 16 + half * 8]);
    Al[m] = *reinterpret_cast<const bf16x8*>(&zel[row * 64 + m * 16 + half * 8]);
  }

  float best[16], bst2[16]; int bidx[16], bidx2[16];
#pragma unroll
  for (int r = 0; r < 16; ++r) { best[r] = 3.4e38f; bst2[r] = 3.4e38f; bidx[r] = 0; bidx2[r] = 0; }

  const int cbase = split * (NCODE / NSPLIT);
  bf16x8 BhA[4], BlA[4], BhB[4], BlB[4];
  float ccA, ccB;

  LOADB(A, 0);
  for (int tt = 0; tt < 32; ++tt) {
    const int t0 = 2 * tt, t1 = 2 * tt + 1;
    LOADB(B, t1);          // prefetch; MFMA+epilogue below hides L2 latency
    MFMAEPI(A, t0);
    if (tt < 31) LOADB(A, t0 + 2);
    MFMAEPI(B, t1);
  }

  // cross-lane top-2 lex merge over the 32 code-columns (xor stays within half)
#pragma unroll
  for (int r = 0; r < 16; ++r) {
    float b1 = best[r], b2 = bst2[r];
    int i1 = bidx[r], i2 = bidx2[r];
#pragma unroll
    for (int m = 1; m < 32; m <<= 1) {
      float ob1 = __shfl_xor(b1, m); int oi1 = __shfl_xor(i1, m);
      float ob2 = __shfl_xor(b2, m); int oi2 = __shfl_xor(i2, m);
      bool aLt = (b1 < ob1) || (b1 == ob1 && i1 < oi1);
      float cs = aLt ? b2 : ob2;  int ci = aLt ? i2 : oi2;
      float ds = aLt ? ob1 : b1;  int di = aLt ? oi1 : i1;
      bool cLt = (cs < ds) || (cs == ds && ci < di);
      b1 = aLt ? b1 : ob1;  i1 = aLt ? i1 : oi1;
      b2 = cLt ? cs : ds;   i2 = cLt ? ci : di;
    }
    if (lr == 0) {
      const int grow = rowBase + (r & 3) + 8 * (r >> 2) + 4 * half;
      pidx[(grow * NSPLIT + split) * 2 + 0] = i1;
      pidx[(grow * NSPLIT + split) * 2 + 1] = i2;
    }
  }
}

// ---------------- kernel 3: exact f32 rescore of 16 nominees + gather + store ----------------
// Thread per (row, nominee). Rescore with r11's bit-exact chain; lex (s, idx) min.
__global__ void kfinal_kernel(const float* __restrict__ ws, const float* __restrict__ cb,
                              float* __restrict__ out)
{
  const int gt = blockIdx.x * 256 + threadIdx.x;
  const int row = gt >> 4;
  const int slot = gt & 15;
  const int* pidx = reinterpret_cast<const int*>(ws + WS_PIDX);
  const float4* cb4 = reinterpret_cast<const float4*>(cb);
  const float4* ze4 = reinterpret_cast<const float4*>(ws + WS_ZE);

  const int cand = pidx[row * 16 + slot] & (NCODE - 1);

  float4 zreg[16];
#pragma unroll
  for (int q = 0; q < 16; ++q) zreg[q] = ze4[row * 16 + q];

  float dot = 0.f;
#pragma unroll
  for (int q = 0; q < 16; ++q) {
    float4 c = cb4[cand * 16 + q];
    dot = fmaf(zreg[q].x, c.x, dot);
    dot = fmaf(zreg[q].y, c.y, dot);
    dot = fmaf(zreg[q].z, c.z, dot);
    dot = fmaf(zreg[q].w, c.w, dot);
  }
  float s = ((ws + WS_ZN)[row] - 2.f * dot) + (ws + WS_CNORM)[cand];  // np order

  float bs = s; int bi = cand;
#pragma unroll
  for (int m = 1; m < 16; m <<= 1) {
    float ob = __shfl_xor(bs, m); int oi = __shfl_xor(bi, m);
    if (ob < bs || (ob == bs && oi < bi)) { bs = ob; bi = oi; }
  }
  if (slot == 0) {
    bi &= (NCODE - 1);
#pragma unroll
    for (int q = 0; q < 16; ++q) {
      float4 c = cb4[bi * 16 + q];
      float4 z = zreg[q];
      float4 r;
      r.x = z.x + (c.x - z.x);
      r.y = z.y + (c.y - z.y);
      r.z = z.z + (c.z - z.z);
      r.w = z.w + (c.w - z.w);
      *reinterpret_cast<float4*>(&out[row * 64 + q * 4]) = r;
    }
    out[BATCH * LAT + row] = (float)bi;
  }
}

extern "C" void kernel_launch(void* const* d_in, const int* in_sizes, int n_in,
                              void* d_out, int out_size, void* d_ws, size_t ws_size,
                              hipStream_t stream)
{
  const float *x = (const float*)d_in[0], *W1 = (const float*)d_in[1],
              *b1 = (const float*)d_in[2], *W2 = (const float*)d_in[3],
              *b2 = (const float*)d_in[4], *cb = (const float*)d_in[5];
  for (int i = 0; i < n_in; ++i) {
    const float* p = (const float*)d_in[i];
    switch (in_sizes[i]) {
      case BATCH * SDIM:  x  = p; break;
      case SDIM * HID:    W1 = p; break;
      case HID:           b1 = p; break;
      case HID * LAT:     W2 = p; break;
      case LAT:           b2 = p; break;
      case NCODE * LAT:   cb = p; break;
      default: break;
    }
  }
  float* ws  = (float*)d_ws;   // ~9.6 MB used
  float* out = (float*)d_out;  // f32: z_q [8192*64] then indices [8192]

  hipLaunchKernelGGL(kprep_kernel, dim3(NCODE / 256), dim3(256), 0, stream, cb, ws);
  hipLaunchKernelGGL(kenc_kernel, dim3(BATCH / 32), dim3(256), 0, stream,
                     x, W1, b1, W2, b2, ws);
  hipLaunchKernelGGL(kdist_kernel, dim3((BATCH / 128) * NSPLIT), dim3(256), 0, stream, ws);
  hipLaunchKernelGGL(kfinal_kernel, dim3(BATCH * 16 / 256), dim3(256), 0, stream,
                     ws, cb, out);
}